// Round 2
// baseline (17223.026 us; speedup 1.0000x reference)
//
#include <hip/hip_runtime.h>
#include <math.h>

#define Tn 256
#define Bn 32
#define Dn 512
#define Hn 512
#define H3n 1536
#define MW 4
#define Ln 2

__device__ __forceinline__ float sigmoidf_(float x){ return 1.f/(1.f+expf(-x)); }

// src[K][N] -> dst[N][K]
__global__ void transpose_kn(const float* __restrict__ src, float* __restrict__ dst, int K, int N){
  int idx = blockIdx.x*256 + threadIdx.x;
  if (idx < K*N){ int k = idx/N, n = idx - k*N; dst[(size_t)n*K + k] = src[idx]; }
}

__global__ void gather_rows(const float* __restrict__ tab, const int* __restrict__ ids,
                            float* __restrict__ out, int rows, int dim){
  int idx = blockIdx.x*256 + threadIdx.x;
  if (idx < rows*dim){ int r = idx/dim, c = idx - r*dim; out[idx] = tab[(size_t)ids[r]*dim + c]; }
}

__global__ void copy_f32(const float* __restrict__ s, float* __restrict__ d, int n){
  for (int i = blockIdx.x*256 + threadIdx.x; i < n; i += gridDim.x*256) d[i] = s[i];
}

// C[M][N] = A[M][K] @ B[K][N] (+ bias[N]);  M%64==0, N%64==0, K%32==0
__global__ __launch_bounds__(256) void gemm_f32(const float* __restrict__ A,
    const float* __restrict__ Bm, const float* __restrict__ bias,
    float* __restrict__ C, int M, int N, int K){
  __shared__ float As[32][65];
  __shared__ float Bs[32][64];
  int nbx = N >> 6;
  int bx = blockIdx.x % nbx, by = blockIdx.x / nbx;
  int row0 = by << 6, col0 = bx << 6;
  int tid = threadIdx.x;
  int tx = tid & 15, ty = tid >> 4;
  float acc[4][4] = {};
  for (int k0 = 0; k0 < K; k0 += 32){
#pragma unroll
    for (int i = 0; i < 8; ++i){
      int idx = tid + (i<<8);
      int m = idx >> 5, k = idx & 31;
      As[k][m] = A[(size_t)(row0+m)*K + k0 + k];
    }
#pragma unroll
    for (int i = 0; i < 8; ++i){
      int idx = tid + (i<<8);
      int k = idx >> 6, n = idx & 63;
      Bs[k][n] = Bm[(size_t)(k0+k)*N + col0 + n];
    }
    __syncthreads();
#pragma unroll
    for (int k = 0; k < 32; ++k){
      float4 b4 = *reinterpret_cast<const float4*>(&Bs[k][tx<<2]);
#pragma unroll
      for (int i = 0; i < 4; ++i){
        float a = As[k][(ty<<2)+i];
        acc[i][0] += a*b4.x; acc[i][1] += a*b4.y; acc[i][2] += a*b4.z; acc[i][3] += a*b4.w;
      }
    }
    __syncthreads();
  }
#pragma unroll
  for (int i = 0; i < 4; ++i){
    int r = row0 + (ty<<2) + i;
#pragma unroll
    for (int jj = 0; jj < 4; ++jj){
      int cc = col0 + (tx<<2) + jj;
      float v = acc[i][jj];
      if (bias) v += bias[cc];
      C[(size_t)r*N + cc] = v;
    }
  }
}

// Phase A of step t: gates, lattice merge, h/c update.
// grid 256x256: 4 lanes per (b,j) output; weights pre-transposed ([n][k], contiguous k).
__global__ __launch_bounds__(256) void step_a(
    const float* __restrict__ xi, const float* __restrict__ xa,
    const float* __restrict__ WhhT, const float* __restrict__ aWhhT,
    const int* __restrict__ wvalid,
    const float* __restrict__ h_prev, const float* __restrict__ c_prev,
    float* __restrict__ h_out, float* __restrict__ c_out,
    const float* __restrict__ wc,
    float* __restrict__ out_t, float* __restrict__ hid_h, float* __restrict__ hid_c,
    int t)
{
  int gid = blockIdx.x*256 + threadIdx.x;
  int grp = gid >> 2, l = gid & 3;
  int b = grp >> 9, j = grp & 511;

  int vm0 = (t >= 1) ? wvalid[(t-1)*MW + 0] : 0;
  int vm1 = (t >= 2) ? wvalid[(t-2)*MW + 1] : 0;
  int vm2 = (t >= 3) ? wvalid[(t-3)*MW + 2] : 0;
  int vm3 = (t >= 4) ? wvalid[(t-4)*MW + 3] : 0;
  int any = vm0 | vm1 | vm2 | vm3;

  const float4* hp  = reinterpret_cast<const float4*>(h_prev + (b<<9));
  const float4* wi4 = reinterpret_cast<const float4*>(WhhT + ((size_t)j << 9));
  const float4* wo4 = reinterpret_cast<const float4*>(WhhT + ((size_t)(j+512) << 9));
  const float4* wg4 = reinterpret_cast<const float4*>(WhhT + ((size_t)(j+1024) << 9));
  const float4* av4 = reinterpret_cast<const float4*>(aWhhT + ((size_t)j << 9));
  const float* ic0 = wc + ((((t-1)&7)*MW + 0)*(Bn*Hn)) + (b<<9);
  const float* ic1 = wc + ((((t-2)&7)*MW + 1)*(Bn*Hn)) + (b<<9);
  const float* ic2 = wc + ((((t-3)&7)*MW + 2)*(Bn*Hn)) + (b<<9);
  const float* ic3 = wc + ((((t-4)&7)*MW + 3)*(Bn*Hn)) + (b<<9);
  const float4* ic04 = reinterpret_cast<const float4*>(ic0);
  const float4* ic14 = reinterpret_cast<const float4*>(ic1);
  const float4* ic24 = reinterpret_cast<const float4*>(ic2);
  const float4* ic34 = reinterpret_cast<const float4*>(ic3);

  float ai=0.f, ao=0.f, ag=0.f, aa0=0.f, aa1=0.f, aa2=0.f, aa3=0.f;
#pragma unroll 8
  for (int it = 0; it < 32; ++it){
    int kk = (it<<2) + l;   // float4 index: floats k = it*16 + l*4 (64B line per 4-lane group)
    float4 h4 = hp[kk];
    float4 w;
    w = wi4[kk]; ai += h4.x*w.x + h4.y*w.y + h4.z*w.z + h4.w*w.w;
    w = wo4[kk]; ao += h4.x*w.x + h4.y*w.y + h4.z*w.z + h4.w*w.w;
    w = wg4[kk]; ag += h4.x*w.x + h4.y*w.y + h4.z*w.z + h4.w*w.w;
    if (any){
      float4 a4 = av4[kk];
      if (vm0){ float4 c4 = ic04[kk]; aa0 += c4.x*a4.x + c4.y*a4.y + c4.z*a4.z + c4.w*a4.w; }
      if (vm1){ float4 c4 = ic14[kk]; aa1 += c4.x*a4.x + c4.y*a4.y + c4.z*a4.z + c4.w*a4.w; }
      if (vm2){ float4 c4 = ic24[kk]; aa2 += c4.x*a4.x + c4.y*a4.y + c4.z*a4.z + c4.w*a4.w; }
      if (vm3){ float4 c4 = ic34[kk]; aa3 += c4.x*a4.x + c4.y*a4.y + c4.z*a4.z + c4.w*a4.w; }
    }
  }
  ai += __shfl_xor(ai,1); ai += __shfl_xor(ai,2);
  ao += __shfl_xor(ao,1); ao += __shfl_xor(ao,2);
  ag += __shfl_xor(ag,1); ag += __shfl_xor(ag,2);
  if (any){
    aa0 += __shfl_xor(aa0,1); aa0 += __shfl_xor(aa0,2);
    aa1 += __shfl_xor(aa1,1); aa1 += __shfl_xor(aa1,2);
    aa2 += __shfl_xor(aa2,1); aa2 += __shfl_xor(aa2,2);
    aa3 += __shfl_xor(aa3,1); aa3 += __shfl_xor(aa3,2);
  }
  if (l == 0){
    int bj = (b<<9) + j;
    const float* xit = xi + (size_t)(t*Bn + b)*H3n;
    float i_ = sigmoidf_(xit[j] + ai);
    float o_ = sigmoidf_(xit[j+512] + ao);
    float g_ = tanhf(xit[j+1024] + ag);
    float c_new;
    if (any){
      float xav = xa[(size_t)(t*Bn + b)*Hn + j];
      float ei = expf(i_);
      float num = ei*g_, den = ei;
      if (vm0){ float al = sigmoidf_(xav + aa0); float ea = expf(al); den += ea; num += ea * ic0[j]; }
      if (vm1){ float al = sigmoidf_(xav + aa1); float ea = expf(al); den += ea; num += ea * ic1[j]; }
      if (vm2){ float al = sigmoidf_(xav + aa2); float ea = expf(al); den += ea; num += ea * ic2[j]; }
      if (vm3){ float al = sigmoidf_(xav + aa3); float ea = expf(al); den += ea; num += ea * ic3[j]; }
      c_new = num/den;
    } else {
      c_new = (1.f - i_)*c_prev[bj] + i_*g_;
    }
    float h_new = o_*tanhf(c_new);
    h_out[bj] = h_new;
    c_out[bj] = c_new;
    out_t[bj] = h_new;
    if (hid_h){ hid_h[bj] = h_new; hid_c[bj] = c_new; }
  }
}

// Phase B of step t: word cells for words starting at t (uses post-update h,c).
__global__ __launch_bounds__(256) void step_b(
    const float* __restrict__ wiw, const float* __restrict__ WwhhT,
    const float* __restrict__ bw, const int* __restrict__ wvalid,
    const float* __restrict__ h_new, const float* __restrict__ c_new,
    float* __restrict__ wc, int t)
{
  int v0 = wvalid[t*MW+0], v1 = wvalid[t*MW+1], v2 = wvalid[t*MW+2], v3 = wvalid[t*MW+3];
  if (!(v0|v1|v2|v3)) return;
  int gid = blockIdx.x*256 + threadIdx.x;
  int grp = gid >> 2, l = gid & 3;
  int b = grp >> 9, j = grp & 511;

  const float4* hp  = reinterpret_cast<const float4*>(h_new + (b<<9));
  const float4* w14 = reinterpret_cast<const float4*>(WwhhT + ((size_t)j << 9));
  const float4* w24 = reinterpret_cast<const float4*>(WwhhT + ((size_t)(j+512) << 9));
  const float4* w34 = reinterpret_cast<const float4*>(WwhhT + ((size_t)(j+1024) << 9));
  float a_i=0.f, a_f=0.f, a_g=0.f;
#pragma unroll 8
  for (int it = 0; it < 32; ++it){
    int kk = (it<<2) + l;
    float4 h4 = hp[kk];
    float4 w;
    w = w14[kk]; a_i += h4.x*w.x + h4.y*w.y + h4.z*w.z + h4.w*w.w;
    w = w24[kk]; a_f += h4.x*w.x + h4.y*w.y + h4.z*w.z + h4.w*w.w;
    w = w34[kk]; a_g += h4.x*w.x + h4.y*w.y + h4.z*w.z + h4.w*w.w;
  }
  a_i += __shfl_xor(a_i,1); a_i += __shfl_xor(a_i,2);
  a_f += __shfl_xor(a_f,1); a_f += __shfl_xor(a_f,2);
  a_g += __shfl_xor(a_g,1); a_g += __shfl_xor(a_g,2);
  if (l == 0){
    int bj = (b<<9) + j;
    float hwi = a_i + bw[j];
    float hwf = a_f + bw[j+512];
    float hwg = a_g + bw[j+1024];
    float cn = c_new[bj];
    int ringbase = (t & 7) * MW;
    const float* wt = wiw + (size_t)(t*MW)*H3n;
    if (v0){ float iw = sigmoidf_(wt[j]+hwi), fw = sigmoidf_(wt[j+512]+hwf), gw = tanhf(wt[j+1024]+hwg);
             wc[(size_t)(ringbase+0)*(Bn*Hn) + bj] = fw*cn + iw*gw; }
    if (v1){ const float* w1 = wt + H3n;
             float iw = sigmoidf_(w1[j]+hwi), fw = sigmoidf_(w1[j+512]+hwf), gw = tanhf(w1[j+1024]+hwg);
             wc[(size_t)(ringbase+1)*(Bn*Hn) + bj] = fw*cn + iw*gw; }
    if (v2){ const float* w2 = wt + 2*H3n;
             float iw = sigmoidf_(w2[j]+hwi), fw = sigmoidf_(w2[j+512]+hwf), gw = tanhf(w2[j+1024]+hwg);
             wc[(size_t)(ringbase+2)*(Bn*Hn) + bj] = fw*cn + iw*gw; }
    if (v3){ const float* w3 = wt + 3*H3n;
             float iw = sigmoidf_(w3[j]+hwi), fw = sigmoidf_(w3[j+512]+hwf), gw = tanhf(w3[j+1024]+hwg);
             wc[(size_t)(ringbase+3)*(Bn*Hn) + bj] = fw*cn + iw*gw; }
  }
}

extern "C" void kernel_launch(void* const* d_in, const int* in_sizes, int n_in,
                              void* d_out, int out_size, void* d_ws, size_t ws_size,
                              hipStream_t stream){
  const float* inputs     = (const float*)d_in[0];
  const float* h0         = (const float*)d_in[1];
  const float* c0         = (const float*)d_in[2];
  const float* gaz        = (const float*)d_in[3];
  const float* W_ih       = (const float*)d_in[4];
  const float* W_hh       = (const float*)d_in[5];
  const float* bias_b     = (const float*)d_in[6];
  const float* aW_ih      = (const float*)d_in[7];
  const float* aW_hh      = (const float*)d_in[8];
  const float* a_b        = (const float*)d_in[9];
  const float* Ww_ih      = (const float*)d_in[10];
  const float* Ww_hh      = (const float*)d_in[11];
  const float* bw         = (const float*)d_in[12];
  const int*   word_ids   = (const int*)d_in[13];
  const int*   word_valid = (const int*)d_in[14];

  float* out    = (float*)d_out;
  float* out_cur = out;                                   // [T,B,H]
  float* out_hh  = out + (size_t)Tn*Bn*Hn;                // [L,B,H]
  float* out_hc  = out_hh + (size_t)Ln*Bn*Hn;             // [L,B,H]
  float* out_all = out_hc + (size_t)Ln*Bn*Hn;             // [L,T,B,H]

  float* p = (float*)d_ws;
  float* WhhT  = p; p += (size_t)H3n*Hn;
  float* aWhhT = p; p += (size_t)Hn*Hn;
  float* WwhhT = p; p += (size_t)H3n*Hn;
  float* wemb  = p; p += (size_t)Tn*MW*Dn;
  float* wiw   = p; p += (size_t)Tn*MW*H3n;
  float* xi    = p; p += (size_t)Tn*Bn*H3n;
  float* xa    = p; p += (size_t)Tn*Bn*Hn;
  float* hb    = p; p += (size_t)2*Bn*Hn;
  float* cb    = p; p += (size_t)2*Bn*Hn;
  float* wc    = p; p += (size_t)8*MW*Bn*Hn;

  transpose_kn<<<(Hn*H3n+255)/256, 256, 0, stream>>>(W_hh,  WhhT,  Hn, H3n);
  transpose_kn<<<(Hn*Hn +255)/256, 256, 0, stream>>>(aW_hh, aWhhT, Hn, Hn);
  transpose_kn<<<(Hn*H3n+255)/256, 256, 0, stream>>>(Ww_hh, WwhhT, Hn, H3n);
  gather_rows<<<(Tn*MW*Dn+255)/256, 256, 0, stream>>>(gaz, word_ids, wemb, Tn*MW, Dn);
  gemm_f32<<<(Tn*MW/64)*(H3n/64), 256, 0, stream>>>(wemb, Ww_ih, nullptr, wiw, Tn*MW, H3n, Dn);

  for (int li = 0; li < Ln; ++li){
    const float* cur = (li == 0) ? inputs : out_all;      // layer-1 input = layer-0 outputs
    gemm_f32<<<(Tn*Bn/64)*(H3n/64), 256, 0, stream>>>(cur, W_ih, bias_b, xi, Tn*Bn, H3n, Dn);
    gemm_f32<<<(Tn*Bn/64)*(Hn/64),  256, 0, stream>>>(cur, aW_ih, a_b,   xa, Tn*Bn, Hn,  Dn);
    copy_f32<<<64, 256, 0, stream>>>(h0 + (size_t)li*Bn*Hn, hb, Bn*Hn);
    copy_f32<<<64, 256, 0, stream>>>(c0 + (size_t)li*Bn*Hn, cb, Bn*Hn);
    for (int t = 0; t < Tn; ++t){
      float* hprev = hb + (t&1)*(Bn*Hn);
      float* cprev = cb + (t&1)*(Bn*Hn);
      float* hnew  = hb + ((t+1)&1)*(Bn*Hn);
      float* cnew  = cb + ((t+1)&1)*(Bn*Hn);
      float* outt  = out_all + ((size_t)li*Tn + t)*Bn*Hn;
      float* hh = (t == Tn-1) ? (out_hh + (size_t)li*Bn*Hn) : nullptr;
      float* hc = (t == Tn-1) ? (out_hc + (size_t)li*Bn*Hn) : nullptr;
      step_a<<<256, 256, 0, stream>>>(xi, xa, WhhT, aWhhT, word_valid,
                                      hprev, cprev, hnew, cnew, wc, outt, hh, hc, t);
      if (t < Tn-1)
        step_b<<<256, 256, 0, stream>>>(wiw, WwhhT, bw, word_valid, hnew, cnew, wc, t);
    }
  }
  copy_f32<<<2048, 256, 0, stream>>>(out_all + (size_t)Tn*Bn*Hn, out_cur, Tn*Bn*Hn);
}